// Round 5
// baseline (137.390 us; speedup 1.0000x reference)
//
#include <hip/hip_runtime.h>

typedef unsigned short u16;
typedef float  f32x4  __attribute__((ext_vector_type(4)));
typedef int    i32x4  __attribute__((ext_vector_type(4)));
typedef __bf16 bf16x8 __attribute__((ext_vector_type(8)));

#define AS1 __attribute__((address_space(1)))
#define AS3 __attribute__((address_space(3)))

__device__ __forceinline__ void gload_lds16(const void* g, void* l) {
  __builtin_amdgcn_global_load_lds((AS1 void*)g, (AS3 void*)l, 16, 0, 0);
}

// Problem constants
constexpr int B_ = 8, T_ = 128, U_ = 64, D_ = 512, V_ = 1024;
constexpr int M_ = B_ * T_ * U_;   // 65536

// ---------------------------------------------------------------------------
// prep_w: W (V,D) f32 -> bf16 ws with XOR-swizzle pre-applied per 64-col
// K-tile (16B chunk c of row v stored at slot c^(v&7)); block 0 also writes
// the lengths pass-through (as f32 values).
// ---------------------------------------------------------------------------
__global__ void prep_w(const float* __restrict__ W,
                       const int* __restrict__ sl, const int* __restrict__ tl,
                       u16* __restrict__ Wb, float* __restrict__ tail) {
  if (blockIdx.x == 0 && threadIdx.x < 16) {
    const int t = threadIdx.x;
    tail[t] = (t < 8) ? (float)sl[t] : (float)tl[t - 8];
  }
  const int tid = blockIdx.x * 256 + threadIdx.x;   // 65536 threads
  const int v  = tid >> 6;
  const int cs = tid & 63;
  const float* sp = W + (size_t)v * D_ + cs * 8;
  float4 w0 = *(const float4*)sp;
  float4 w1 = *(const float4*)(sp + 4);
  union { __bf16 h[8]; i32x4 x; } pk;
  pk.h[0] = (__bf16)w0.x; pk.h[1] = (__bf16)w0.y;
  pk.h[2] = (__bf16)w0.z; pk.h[3] = (__bf16)w0.w;
  pk.h[4] = (__bf16)w1.x; pk.h[5] = (__bf16)w1.y;
  pk.h[6] = (__bf16)w1.z; pk.h[7] = (__bf16)w1.w;
  const int dc = (cs >> 3) * 8 + ((cs & 7) ^ (v & 7));
  *(i32x4*)(Wb + (size_t)v * D_ + dc * 8) = pk.x;
}

__global__ void tail_k(const int* __restrict__ sl, const int* __restrict__ tl,
                       float* __restrict__ tail) {
  const int t = threadIdx.x;
  if (t < 8)       tail[t] = (float)sl[t];
  else if (t < 16) tail[t] = (float)tl[t - 8];
}

// ---------------------------------------------------------------------------
// Fused joiner GEMM: BM=128, BN=256, BK=64, 512 threads (8 waves 2Mx4N),
// wave tile 64x64, 4x4 x mfma_f32_16x16x32_bf16.
// R1's proven 2-barrier single-buffer backbone; BN=256 halves the A-expansion
// redundancy (4x instead of 8x chip-wide) and per-thread expand work.
// LDS 48KB -> 2 blocks/CU (16 waves) with VGPR<=128 (launch_bounds(512,4)).
// A-expand: each thread covers 2 chunks of one row. B: global_load_lds of
// pre-swizzled bf16 W. Bias folded into accumulator init.
// ---------------------------------------------------------------------------
__global__ __launch_bounds__(512, 4) void joiner_gemm(
    const float* __restrict__ src, const float* __restrict__ tgt,
    const u16* __restrict__ Wb, const float* __restrict__ bias,
    float* __restrict__ out)
{
  __shared__ __align__(16) char As[16384];   // 128 rows x 64 bf16
  __shared__ __align__(16) char Bs[32768];   // 256 rows x 64 bf16

  const int tid  = threadIdx.x;
  const int lane = tid & 63;
  const int wid  = tid >> 6;
  // XCD swizzle: xcd = wgid&7 (round-robin dispatch). Each XCD owns one
  // bn slice (W slice 256KB, L2-resident) x half the bm range.
  const int wgid = blockIdx.x;               // 0..2047
  const int xcd  = wgid & 7;
  const int idx  = wgid >> 3;                // 0..255
  const int bn   = xcd >> 1;                 // 0..3
  const int bmi  = idx * 2 + (xcd & 1);      // 0..511
  const int bt0  = bmi * 2;                  // two (b,t) rows per 128-row tile
  const int bb   = bmi >> 6;                 // batch
  const int wm   = (wid >> 2) * 64;          // wave M offset (0/64)
  const int wn   = (wid & 3) * 64;           // wave N offset (0..192)

  // --- accumulators, bias-initialized (C/D frag: all 4 regs share col) ---
  f32x4 acc[4][4];
  #pragma unroll
  for (int ni = 0; ni < 4; ++ni) {
    const float bv = bias[bn * 256 + wn + ni * 16 + (lane & 15)];
    #pragma unroll
    for (int mi = 0; mi < 4; ++mi) acc[mi][ni] = f32x4{bv, bv, bv, bv};
  }

  // --- A staging: thread covers row r0, chunks c0 and c0+1 ---
  const int r0 = tid >> 2;                   // 0..127
  const int c0 = (tid & 3) * 2;              // 0,2,4,6
  const int bt = bt0 + (r0 >> 6);
  const int u  = r0 & 63;
  const float* srcp = src + (size_t)bt * D_ + c0 * 8;
  const float* tgtp = tgt + ((size_t)bb * U_ + u) * D_ + c0 * 8;
  char* aw0 = As + r0 * 128 + ((c0 ^ (r0 & 7)) << 4);
  char* aw1 = As + r0 * 128 + (((c0 + 1) ^ (r0 & 7)) << 4);

  // --- B staging bases: 32 x 1KB stripes, 4 per wave ---
  const u16* bbase[4];
  #pragma unroll
  for (int q = 0; q < 4; ++q) {
    const int i   = wid * 4 + q;
    const int row = i * 8 + (lane >> 3);
    bbase[q] = Wb + (size_t)(bn * 256 + row) * D_ + (lane & 7) * 8;
  }

  for (int kt = 0; kt < 8; ++kt) {
    const int k0 = kt * 64;
    if (kt > 0) __syncthreads();             // guard LDS overwrite

    // B DMA (in flight under the expand VALU below)
    #pragma unroll
    for (int q = 0; q < 4; ++q)
      gload_lds16(bbase[q] + k0, Bs + (wid * 4 + q) * 1024);

    // A expand: relu(src+tgt) -> bf16, swizzled ds_write (2 chunks)
    {
      float4 s0 = *(const float4*)(srcp + k0);
      float4 s1 = *(const float4*)(srcp + k0 + 4);
      float4 s2 = *(const float4*)(srcp + k0 + 8);
      float4 s3 = *(const float4*)(srcp + k0 + 12);
      float4 t0 = *(const float4*)(tgtp + k0);
      float4 t1 = *(const float4*)(tgtp + k0 + 4);
      float4 t2 = *(const float4*)(tgtp + k0 + 8);
      float4 t3 = *(const float4*)(tgtp + k0 + 12);
      union { __bf16 h[8]; i32x4 x; } pk;
      pk.h[0] = (__bf16)fmaxf(s0.x + t0.x, 0.f);
      pk.h[1] = (__bf16)fmaxf(s0.y + t0.y, 0.f);
      pk.h[2] = (__bf16)fmaxf(s0.z + t0.z, 0.f);
      pk.h[3] = (__bf16)fmaxf(s0.w + t0.w, 0.f);
      pk.h[4] = (__bf16)fmaxf(s1.x + t1.x, 0.f);
      pk.h[5] = (__bf16)fmaxf(s1.y + t1.y, 0.f);
      pk.h[6] = (__bf16)fmaxf(s1.z + t1.z, 0.f);
      pk.h[7] = (__bf16)fmaxf(s1.w + t1.w, 0.f);
      *(i32x4*)aw0 = pk.x;
      pk.h[0] = (__bf16)fmaxf(s2.x + t2.x, 0.f);
      pk.h[1] = (__bf16)fmaxf(s2.y + t2.y, 0.f);
      pk.h[2] = (__bf16)fmaxf(s2.z + t2.z, 0.f);
      pk.h[3] = (__bf16)fmaxf(s2.w + t2.w, 0.f);
      pk.h[4] = (__bf16)fmaxf(s3.x + t3.x, 0.f);
      pk.h[5] = (__bf16)fmaxf(s3.y + t3.y, 0.f);
      pk.h[6] = (__bf16)fmaxf(s3.z + t3.z, 0.f);
      pk.h[7] = (__bf16)fmaxf(s3.w + t3.w, 0.f);
      *(i32x4*)aw1 = pk.x;
    }
    __syncthreads();                         // staging complete (vm+lgkm)

    // compute: 2 k-steps x (4+4 ds_read_b128 + 16 MFMA)
    #pragma unroll
    for (int s = 0; s < 2; ++s) {
      const int kc = s * 4 + (lane >> 4);
      bf16x8 af[4], bg[4];
      #pragma unroll
      for (int mi = 0; mi < 4; ++mi) {
        const int r = wm + mi * 16 + (lane & 15);
        af[mi] = *(const bf16x8*)(As + r * 128 + ((kc ^ (r & 7)) << 4));
      }
      #pragma unroll
      for (int ni = 0; ni < 4; ++ni) {
        const int n = wn + ni * 16 + (lane & 15);
        bg[ni] = *(const bf16x8*)(Bs + n * 128 + ((kc ^ (n & 7)) << 4));
      }
      __builtin_amdgcn_s_setprio(1);
      #pragma unroll
      for (int mi = 0; mi < 4; ++mi)
        #pragma unroll
        for (int ni = 0; ni < 4; ++ni)
          acc[mi][ni] = __builtin_amdgcn_mfma_f32_16x16x32_bf16(
              af[mi], bg[ni], acc[mi][ni], 0, 0, 0);
      __builtin_amdgcn_s_setprio(0);
    }
  }

  // epilogue: C/D layout col=lane&15, row=(lane>>4)*4+reg (bias pre-folded)
  const int col = lane & 15;
  const int r4  = (lane >> 4) * 4;
  #pragma unroll
  for (int mi = 0; mi < 4; ++mi) {
    const size_t mrow = (size_t)bmi * 128 + wm + mi * 16 + r4;
    float* op0 = out + mrow * V_ + bn * 256 + wn + col;
    #pragma unroll
    for (int ni = 0; ni < 4; ++ni) {
      float* op = op0 + ni * 16;
      const f32x4 v = acc[mi][ni];
      op[0 * V_] = v[0];
      op[1 * V_] = v[1];
      op[2 * V_] = v[2];
      op[3 * V_] = v[3];
    }
  }
}

// ---------------------------------------------------------------------------
// Fallback (ws too small): round-1 fused kernel, f32 W in-loop.
// ---------------------------------------------------------------------------
__global__ __launch_bounds__(256, 2) void joiner_gemm_f32(
    const float* __restrict__ src, const float* __restrict__ tgt,
    const float* __restrict__ Wf, const float* __restrict__ bias,
    float* __restrict__ out)
{
  __shared__ char As[128 * 128];
  __shared__ char Bs[128 * 128];

  const int tid  = threadIdx.x;
  const int lane = tid & 63;
  const int wid  = tid >> 6;
  const int bn   = blockIdx.x & 7;
  const int bm   = blockIdx.x >> 3;
  const int bt0  = bm * 2;
  const int bb   = bt0 >> 7;
  const int sr0  = tid >> 3;
  const int sc8  = tid & 7;
  const int wm   = (wid >> 1) * 64;
  const int wn   = (wid & 1) * 64;

  f32x4 acc[4][4] = {};

  const float* srcp0 = src + (size_t)bt0 * D_ + sc8 * 8;
  const float* srcp1 = srcp0 + D_;
  const float* tgtp0 = tgt + ((size_t)bb * U_ + sr0) * D_ + sc8 * 8;
  const float* tgtp1 = tgtp0 + (size_t)32 * D_;

  for (int kt = 0; kt < 8; ++kt) {
    const int k0 = kt * 64;
    #pragma unroll
    for (int jj = 0; jj < 4; ++jj) {
      const int vr = sr0 + 32 * jj;
      const float* wp = Wf + (size_t)(bn * 128 + vr) * D_ + k0 + sc8 * 8;
      float4 w0 = *(const float4*)wp;
      float4 w1 = *(const float4*)(wp + 4);
      union { __bf16 h[8]; i32x4 x; } pk;
      pk.h[0] = (__bf16)w0.x; pk.h[1] = (__bf16)w0.y;
      pk.h[2] = (__bf16)w0.z; pk.h[3] = (__bf16)w0.w;
      pk.h[4] = (__bf16)w1.x; pk.h[5] = (__bf16)w1.y;
      pk.h[6] = (__bf16)w1.z; pk.h[7] = (__bf16)w1.w;
      *(i32x4*)(Bs + vr * 128 + ((sc8 ^ (vr & 7)) << 4)) = pk.x;
    }
    float4 s0a = *(const float4*)(srcp0 + k0), s0b = *(const float4*)(srcp0 + k0 + 4);
    float4 s1a = *(const float4*)(srcp1 + k0), s1b = *(const float4*)(srcp1 + k0 + 4);
    float4 t0a = *(const float4*)(tgtp0 + k0), t0b = *(const float4*)(tgtp0 + k0 + 4);
    float4 t1a = *(const float4*)(tgtp1 + k0), t1b = *(const float4*)(tgtp1 + k0 + 4);
    #pragma unroll
    for (int i = 0; i < 2; ++i) {
      const float4 sa = i ? s1a : s0a;
      const float4 sb = i ? s1b : s0b;
      #pragma unroll
      for (int jj = 0; jj < 2; ++jj) {
        const float4 ta = jj ? t1a : t0a;
        const float4 tb = jj ? t1b : t0b;
        const int r = i * 64 + jj * 32 + sr0;
        union { __bf16 h[8]; i32x4 x; } pk;
        pk.h[0] = (__bf16)fmaxf(sa.x + ta.x, 0.f);
        pk.h[1] = (__bf16)fmaxf(sa.y + ta.y, 0.f);
        pk.h[2] = (__bf16)fmaxf(sa.z + ta.z, 0.f);
        pk.h[3] = (__bf16)fmaxf(sa.w + ta.w, 0.f);
        pk.h[4] = (__bf16)fmaxf(sb.x + tb.x, 0.f);
        pk.h[5] = (__bf16)fmaxf(sb.y + tb.y, 0.f);
        pk.h[6] = (__bf16)fmaxf(sb.z + tb.z, 0.f);
        pk.h[7] = (__bf16)fmaxf(sb.w + tb.w, 0.f);
        *(i32x4*)(As + r * 128 + ((sc8 ^ (r & 7)) << 4)) = pk.x;
      }
    }
    __syncthreads();
    #pragma unroll
    for (int s = 0; s < 2; ++s) {
      const int kc = s * 4 + (lane >> 4);
      bf16x8 af[4], bg[4];
      #pragma unroll
      for (int mi = 0; mi < 4; ++mi) {
        const int r = wm + mi * 16 + (lane & 15);
        af[mi] = *(const bf16x8*)(As + r * 128 + ((kc ^ (r & 7)) << 4));
      }
      #pragma unroll
      for (int ni = 0; ni < 4; ++ni) {
        const int n = wn + ni * 16 + (lane & 15);
        bg[ni] = *(const bf16x8*)(Bs + n * 128 + ((kc ^ (n & 7)) << 4));
      }
      #pragma unroll
      for (int mi = 0; mi < 4; ++mi)
        #pragma unroll
        for (int ni = 0; ni < 4; ++ni)
          acc[mi][ni] = __builtin_amdgcn_mfma_f32_16x16x32_bf16(
              af[mi], bg[ni], acc[mi][ni], 0, 0, 0);
    }
    __syncthreads();
  }

  const int col = lane & 15;
  const int r4  = (lane >> 4) * 4;
  float bv[4];
  #pragma unroll
  for (int ni = 0; ni < 4; ++ni) bv[ni] = bias[bn * 128 + wn + ni * 16 + col];
  #pragma unroll
  for (int mi = 0; mi < 4; ++mi) {
    const size_t mrow = (size_t)bm * 128 + wm + mi * 16 + r4;
    float* op0 = out + mrow * V_ + bn * 128 + wn + col;
    #pragma unroll
    for (int ni = 0; ni < 4; ++ni) {
      float* op = op0 + ni * 16;
      const f32x4 v = acc[mi][ni];
      op[0 * V_] = v[0] + bv[ni];
      op[1 * V_] = v[1] + bv[ni];
      op[2 * V_] = v[2] + bv[ni];
      op[3 * V_] = v[3] + bv[ni];
    }
  }
}

extern "C" void kernel_launch(void* const* d_in, const int* in_sizes, int n_in,
                              void* d_out, int out_size, void* d_ws, size_t ws_size,
                              hipStream_t stream) {
  const float* src  = (const float*)d_in[0];
  const int*   sl   = (const int*)d_in[1];
  const float* tgt  = (const float*)d_in[2];
  const int*   tl   = (const int*)d_in[3];
  const float* W    = (const float*)d_in[4];
  const float* bias = (const float*)d_in[5];
  float* out  = (float*)d_out;
  float* tail = out + (size_t)M_ * V_;

  if (ws_size >= (size_t)V_ * D_ * sizeof(u16)) {
    u16* Wb = (u16*)d_ws;
    prep_w<<<256, 256, 0, stream>>>(W, sl, tl, Wb, tail);
    joiner_gemm<<<(M_ / 128) * (V_ / 256), 512, 0, stream>>>(
        src, tgt, Wb, bias, out);
  } else {
    tail_k<<<1, 64, 0, stream>>>(sl, tl, tail);
    joiner_gemm_f32<<<(M_ / 128) * (V_ / 128), 256, 0, stream>>>(
        src, tgt, W, bias, out);
  }
}